// Round 3
// baseline (583.566 us; speedup 1.0000x reference)
//
#include <hip/hip_runtime.h>
#include <stdint.h>

typedef unsigned int u32;
typedef unsigned short u16;

#define LN_EPS_ 1e-5f
#define EPS_ 1e-8f

__device__ __forceinline__ float bflo(u32 v){ return __uint_as_float(v << 16); }
__device__ __forceinline__ float bfhi(u32 v){ return __uint_as_float(v & 0xFFFF0000u); }
__device__ __forceinline__ u32 f2bf(float f){
    u32 x = __float_as_uint(f);
    return (x + 0x7FFFu + ((x >> 16) & 1u)) >> 16;
}

// ---------------- kernel 0: slots init -------------------------------------
// slots[b,s,h] = mu[h] + exp(log_sigma[h]) * slots_init[b,s,h]  (first 128 of 132)
__global__ __launch_bounds__(256) void k_init_slots(
    const float* __restrict__ slots_init, const float* __restrict__ mu,
    const float* __restrict__ ls, float* __restrict__ slots)
{
    int i = blockIdx.x * 256 + threadIdx.x;
    if (i >= 64 * 7 * 128) return;
    int h = i & 127;
    int bs = i >> 7;
    slots[i] = mu[h] + expf(ls[h]) * slots_init[bs * 132 + h];
}

// ---------------- kernel 1: per-(b,s) slot prep ----------------------------
// sn = LN(slots); q = Wq@sn; r = scale*Wk^T@q;
// rws[b][s][d] = g_in[d]*r[d]; c1 = sum(g_in*r); c2 = sum(b_in*r)
// also zeroes yws/Zws/Aws for this iteration.
__global__ __launch_bounds__(128) void k_slots_prep(
    const float* __restrict__ slots,
    const float* __restrict__ g_s, const float* __restrict__ b_s,
    const float* __restrict__ Wq, const float* __restrict__ Wk,
    const float* __restrict__ g_in, const float* __restrict__ b_in,
    float* __restrict__ rws, float* __restrict__ c1ws, float* __restrict__ c2ws,
    float* __restrict__ yws, float* __restrict__ Zws, float* __restrict__ Aws)
{
    __shared__ float snb[128], qb[128];
    __shared__ float redA[2], redB[2], redC[2], redD[2];
    int bs = blockIdx.x, t = threadIdx.x;
    int b = bs / 7, s = bs - b * 7;
    int lane = t & 63, wvi = t >> 6;
    float sv = slots[bs * 128 + t];
    float sm = sv, sq = sv * sv;
    for (int m = 32; m >= 1; m >>= 1) { sm += __shfl_xor(sm, m); sq += __shfl_xor(sq, m); }
    if (lane == 0) { redA[wvi] = sm; redB[wvi] = sq; }
    __syncthreads();
    sm = redA[0] + redA[1]; sq = redB[0] + redB[1];
    float mean = sm * (1.0f / 128.0f);
    float var  = sq * (1.0f / 128.0f) - mean * mean;
    float rs = rsqrtf(var + LN_EPS_);
    snb[t] = (sv - mean) * rs * g_s[t] + b_s[t];
    __syncthreads();
    const float2* Wq2 = (const float2*)Wq;
    float q = 0.f;
    for (int d2 = 0; d2 < 64; d2++) {
        float2 wv = Wq2[t * 64 + d2];
        q += wv.x * snb[2 * d2] + wv.y * snb[2 * d2 + 1];
    }
    qb[t] = q;
    __syncthreads();
    float r = 0.f;
    for (int j = 0; j < 128; j++)
        r += Wk[j * 128 + t] * qb[j];            // (Wk^T q)[t], coalesced over t
    r *= 0.08838834764831845f;                    // 128^-0.5
    float rt  = g_in[t] * r;
    float c2v = b_in[t] * r;
    rws[((size_t)b * 8 + s) * 128 + t] = rt;
    float c1p = rt, c2p = c2v;
    for (int m = 32; m >= 1; m >>= 1) { c1p += __shfl_xor(c1p, m); c2p += __shfl_xor(c2p, m); }
    if (lane == 0) { redC[wvi] = c1p; redD[wvi] = c2p; }
    yws[bs * 128 + t] = 0.f;
    __syncthreads();
    if (t == 0) {
        c1ws[b * 8 + s] = redC[0] + redC[1];
        c2ws[b * 8 + s] = redD[0] + redD[1];
        Zws[b * 8 + s] = 0.f;
        Aws[b * 8 + s] = 0.f;
    }
}

// ---------------- kernel 2: streaming attention over raw fp32 x ------------
// block = 128 threads, chunk = 128 rows of one batch. LN folded analytically:
//   logit_s = rs*(x.rt_s - mean*c1_s) + c2_s, rt = g_in ⊙ (scale*Wk^T q_s)
// phase1: thread t owns row n0+t: dots+stats from fp32, softmax, w = p*rs;
//         packs raw x to bf16 LDS tile for phase2.
// phase2: thread accumulates ytilde[s][d] = sum_n w[n][s]*x[n][d]
__global__ __launch_bounds__(128) void k_attn(
    const float* __restrict__ xin,
    const float* __restrict__ rws, const float* __restrict__ c1ws,
    const float* __restrict__ c2ws,
    float* __restrict__ yws, float* __restrict__ Zws, float* __restrict__ Aws)
{
    __shared__ u32 tile[128 * 68];               // 128 rows x 64 u32 (bf16x2), pad 4
    __shared__ float wl[128 * 9];                // w per row, 7 slots + zero pad
    __shared__ float redp[2][8], redw[2][8];
    int t = threadIdx.x;
    int b = blockIdx.y;
    int n0 = blockIdx.x * 128;
    int lane = t & 63, wvi = t >> 6;
    const float4* xr = (const float4*)(xin + ((size_t)(b * 4096 + n0 + t)) * 128);
    const float* rr = rws + (size_t)b * 1024;    // [8][128], wave-uniform reads
    uint2* trow = (uint2*)&tile[t * 68];

    float a[7];
    #pragma unroll
    for (int s = 0; s < 7; s++) a[s] = 0.f;
    float sm = 0.f, sq = 0.f;
    #pragma unroll 4
    for (int j = 0; j < 32; j++) {
        float4 v = xr[j];
        int d0 = j * 4;
        sm += v.x + v.y + v.z + v.w;
        sq += v.x * v.x + v.y * v.y + v.z * v.z + v.w * v.w;
        #pragma unroll
        for (int s = 0; s < 7; s++) {
            const float* rrs = rr + s * 128 + d0;
            a[s] += v.x * rrs[0] + v.y * rrs[1] + v.z * rrs[2] + v.w * rrs[3];
        }
        uint2 pk;
        pk.x = f2bf(v.x) | (f2bf(v.y) << 16);
        pk.y = f2bf(v.z) | (f2bf(v.w) << 16);
        trow[j] = pk;
    }
    float mean = sm * (1.0f / 128.0f);
    float var  = sq * (1.0f / 128.0f) - mean * mean;
    float rs = rsqrtf(var + LN_EPS_);
    float L[7], mx = -3.4e38f;
    #pragma unroll
    for (int s = 0; s < 7; s++) {
        L[s] = rs * (a[s] - mean * c1ws[b * 8 + s]) + c2ws[b * 8 + s];
        mx = fmaxf(mx, L[s]);
    }
    float ssum = 0.f;
    #pragma unroll
    for (int s = 0; s < 7; s++) { L[s] = __expf(L[s] - mx); ssum += L[s]; }
    float inv = 1.0f / ssum;
    float p[7], w[7];
    #pragma unroll
    for (int s = 0; s < 7; s++) { p[s] = L[s] * inv + EPS_; w[s] = p[s] * rs; }
    #pragma unroll
    for (int s = 0; s < 7; s++) {
        float z = p[s], aa = w[s] * mean;
        for (int m = 32; m >= 1; m >>= 1) { z += __shfl_xor(z, m); aa += __shfl_xor(aa, m); }
        if (lane == 0) { redp[wvi][s] = z; redw[wvi][s] = aa; }
        wl[t * 9 + s] = w[s];
    }
    wl[t * 9 + 7] = 0.f;                         // pad slot for dummy item
    __syncthreads();
    if (t < 7)                    atomicAdd(&Zws[b * 8 + t], redp[0][t] + redp[1][t]);
    else if (t >= 64 && t < 71) { int s = t - 64; atomicAdd(&Aws[b * 8 + s], redw[0][s] + redw[1][s]); }

    // phase2: thread = (dp = lane, s = wvi + 2k for k=0..3; s==7 is dummy)
    int dp = lane, sA = wvi;
    float accl[4] = {0.f, 0.f, 0.f, 0.f}, acch[4] = {0.f, 0.f, 0.f, 0.f};
    #pragma unroll 4
    for (int n = 0; n < 128; n++) {
        u32 xv = tile[n * 68 + dp];
        float f0 = bflo(xv), f1 = bfhi(xv);
        const float* wr = &wl[n * 9];
        float w0 = wr[sA], w1 = wr[sA + 2], w2 = wr[sA + 4], w3 = wr[sA + 6];
        accl[0] += f0 * w0; acch[0] += f1 * w0;
        accl[1] += f0 * w1; acch[1] += f1 * w1;
        accl[2] += f0 * w2; acch[2] += f1 * w2;
        accl[3] += f0 * w3; acch[3] += f1 * w3;
    }
    float* yb = yws + (size_t)b * 7 * 128;
    #pragma unroll
    for (int k = 0; k < 4; k++) {
        int s = sA + 2 * k;
        if (s < 7) {
            atomicAdd(&yb[s * 128 + 2 * dp],     accl[k]);
            atomicAdd(&yb[s * 128 + 2 * dp + 1], acch[k]);
        }
    }
}

// ---------------- kernel 3: per-(b,s) slot update (GRU + MLP) --------------
// y_s[d] = g_in[d]*(ytilde - A)/Z + b_in[d]; u = Wv@y; GRU; +MLP residual
__global__ __launch_bounds__(128) void k_update(
    float* __restrict__ slots, const float* __restrict__ yws,
    const float* __restrict__ Zws, const float* __restrict__ Aws,
    const float* __restrict__ g_in, const float* __restrict__ b_in,
    const float* __restrict__ Wv, const float* __restrict__ W_ih,
    const float* __restrict__ W_hh, const float* __restrict__ b_ih,
    const float* __restrict__ b_hh, const float* __restrict__ g_m,
    const float* __restrict__ b_m, const float* __restrict__ w1,
    const float* __restrict__ bb1, const float* __restrict__ w2,
    const float* __restrict__ bb2, float* __restrict__ out)
{
    __shared__ float ybuf[128], ub[128], hb[128], lb[128], t1b[256];
    __shared__ float redA[2], redB[2];
    int bs = blockIdx.x, t = threadIdx.x;
    int b = bs / 7, s = bs - b * 7;
    int lane = t & 63, wvi = t >> 6;
    float Z = Zws[b * 8 + s], A = Aws[b * 8 + s];
    float invZ = 1.0f / Z;
    ybuf[t] = g_in[t] * (yws[bs * 128 + t] - A) * invZ + b_in[t];
    hb[t] = slots[bs * 128 + t];
    __syncthreads();
    const float2* Wv2 = (const float2*)Wv;
    float acc = 0.f;
    for (int d2 = 0; d2 < 64; d2++) {
        float2 wv = Wv2[t * 64 + d2];
        acc += wv.x * ybuf[2 * d2] + wv.y * ybuf[2 * d2 + 1];
    }
    ub[t] = acc;
    __syncthreads();
    const float2* Wih2 = (const float2*)W_ih;
    const float2* Whh2 = (const float2*)W_hh;
    float gi[3], gh[3];
    #pragma unroll
    for (int k = 0; k < 3; k++) {
        int j = k * 128 + t;
        float ai = b_ih[j], ah = b_hh[j];
        for (int d2 = 0; d2 < 64; d2++) {
            float2 wi = Wih2[j * 64 + d2];
            float2 wh = Whh2[j * 64 + d2];
            ai += wi.x * ub[2 * d2] + wi.y * ub[2 * d2 + 1];
            ah += wh.x * hb[2 * d2] + wh.y * hb[2 * d2 + 1];
        }
        gi[k] = ai; gh[k] = ah;
    }
    float rg = 1.0f / (1.0f + __expf(-(gi[0] + gh[0])));
    float zg = 1.0f / (1.0f + __expf(-(gi[1] + gh[1])));
    float ng = tanhf(gi[2] + rg * gh[2]);
    float hv = (1.0f - zg) * ng + zg * hb[t];
    float sm2 = hv, sq2 = hv * hv;
    for (int m = 32; m >= 1; m >>= 1) { sm2 += __shfl_xor(sm2, m); sq2 += __shfl_xor(sq2, m); }
    if (lane == 0) { redA[wvi] = sm2; redB[wvi] = sq2; }
    __syncthreads();
    sm2 = redA[0] + redA[1]; sq2 = redB[0] + redB[1];
    float mean = sm2 * (1.0f / 128.0f);
    float var  = sq2 * (1.0f / 128.0f) - mean * mean;
    float rsq = rsqrtf(var + LN_EPS_);
    lb[t] = (hv - mean) * rsq * g_m[t] + b_m[t];
    __syncthreads();
    const float2* w12 = (const float2*)w1;
    #pragma unroll
    for (int k = 0; k < 2; k++) {
        int j = k * 128 + t;
        float aa = bb1[j];
        for (int d2 = 0; d2 < 64; d2++) {
            float2 wv = w12[j * 64 + d2];
            aa += wv.x * lb[2 * d2] + wv.y * lb[2 * d2 + 1];
        }
        t1b[j] = fmaxf(aa, 0.0f);
    }
    __syncthreads();
    const float2* w22 = (const float2*)w2;
    float o = hv + bb2[t];
    for (int j2 = 0; j2 < 128; j2++) {
        float2 wv = w22[t * 128 + j2];
        o += wv.x * t1b[2 * j2] + wv.y * t1b[2 * j2 + 1];
    }
    slots[bs * 128 + t] = o;
    out[bs * 128 + t] = o;
}

extern "C" void kernel_launch(void* const* d_in, const int* in_sizes, int n_in,
                              void* d_out, int out_size, void* d_ws, size_t ws_size,
                              hipStream_t stream) {
    const float* inputs     = (const float*)d_in[0];
    const float* slots_init = (const float*)d_in[1];
    const float* ln_in_g    = (const float*)d_in[2];
    const float* ln_in_b    = (const float*)d_in[3];
    const float* ln_s_g     = (const float*)d_in[4];
    const float* ln_s_b     = (const float*)d_in[5];
    const float* ln_m_g     = (const float*)d_in[6];
    const float* ln_m_b     = (const float*)d_in[7];
    const float* Wq         = (const float*)d_in[8];
    const float* Wk         = (const float*)d_in[9];
    const float* Wv         = (const float*)d_in[10];
    const float* W_ih       = (const float*)d_in[11];
    const float* W_hh       = (const float*)d_in[12];
    const float* b_ih       = (const float*)d_in[13];
    const float* b_hh       = (const float*)d_in[14];
    const float* mlp_w1     = (const float*)d_in[15];
    const float* mlp_b1     = (const float*)d_in[16];
    const float* mlp_w2     = (const float*)d_in[17];
    const float* mlp_b2     = (const float*)d_in[18];
    const float* slots_mu   = (const float*)d_in[19];
    const float* slots_ls   = (const float*)d_in[20];

    char* ws = (char*)d_ws;
    float* slots = (float*)(ws);                 // 64*7*128 f32 = 229376 B
    float* rws   = (float*)(ws + 229376);        // 64*8*128 f32 = 262144 B
    float* c1ws  = (float*)(ws + 491520);        // 2048 B
    float* c2ws  = (float*)(ws + 493568);        // 2048 B
    float* yws   = (float*)(ws + 495616);        // 229376 B
    float* Zws   = (float*)(ws + 724992);        // 2048 B
    float* Aws   = (float*)(ws + 727040);        // 2048 B  (total ~712 KB)

    k_init_slots<<<224, 256, 0, stream>>>(slots_init, slots_mu, slots_ls, slots);
    for (int it = 0; it < 3; it++) {
        k_slots_prep<<<448, 128, 0, stream>>>(slots, ln_s_g, ln_s_b, Wq, Wk,
                                              ln_in_g, ln_in_b,
                                              rws, c1ws, c2ws, yws, Zws, Aws);
        k_attn<<<dim3(32, 64), 128, 0, stream>>>(inputs, rws, c1ws, c2ws, yws, Zws, Aws);
        k_update<<<448, 128, 0, stream>>>(slots, yws, Zws, Aws, ln_in_g, ln_in_b,
                                          Wv, W_ih, W_hh, b_ih, b_hh,
                                          ln_m_g, ln_m_b, mlp_w1, mlp_b1, mlp_w2, mlp_b2,
                                          (float*)d_out);
    }
}

// Round 4
// 466.834 us; speedup vs baseline: 1.2501x; 1.2501x over previous
//
#include <hip/hip_runtime.h>
#include <stdint.h>

typedef unsigned int u32;
typedef unsigned short u16;

#define LN_EPS_ 1e-5f
#define EPS_ 1e-8f

__device__ __forceinline__ float bflo(u32 v){ return __uint_as_float(v << 16); }
__device__ __forceinline__ float bfhi(u32 v){ return __uint_as_float(v & 0xFFFF0000u); }
__device__ __forceinline__ u32 f2bf(float f){
    u32 x = __float_as_uint(f);
    return (x + 0x7FFFu + ((x >> 16) & 1u)) >> 16;
}

// ---------------- kernel T: one-time weight transposes ---------------------
// 64x64 tiles through LDS; all reads/writes coalesced.
__global__ __launch_bounds__(256) void k_twt(
    const float* __restrict__ Wq, const float* __restrict__ Wv,
    const float* __restrict__ Wih, const float* __restrict__ Whh,
    const float* __restrict__ w1, const float* __restrict__ w2,
    float* __restrict__ WqT, float* __restrict__ WvT, float* __restrict__ WihT,
    float* __restrict__ WhhT, float* __restrict__ w1T, float* __restrict__ w2T)
{
    __shared__ float T[64][65];
    int bid = blockIdx.x;
    const float* src; float* dst; int R, C, tr, tc;
    if (bid < 4)       { src = Wq;  dst = WqT;  R = 128; C = 128; int l = bid;      tr = l >> 1; tc = l & 1; }
    else if (bid < 8)  { src = Wv;  dst = WvT;  R = 128; C = 128; int l = bid - 4;  tr = l >> 1; tc = l & 1; }
    else if (bid < 20) { src = Wih; dst = WihT; R = 384; C = 128; int l = bid - 8;  tr = l >> 1; tc = l & 1; }
    else if (bid < 32) { src = Whh; dst = WhhT; R = 384; C = 128; int l = bid - 20; tr = l >> 1; tc = l & 1; }
    else if (bid < 40) { src = w1;  dst = w1T;  R = 256; C = 128; int l = bid - 32; tr = l >> 1; tc = l & 1; }
    else               { src = w2;  dst = w2T;  R = 128; C = 256; int l = bid - 40; tr = l >> 2; tc = l & 3; }
    int r0 = tr * 64, c0 = tc * 64;
    int tt = threadIdx.x;
    int lr = tt >> 6, lc = tt & 63;
    #pragma unroll
    for (int i = 0; i < 16; i++) {
        int r = i * 4 + lr;
        T[r][lc] = src[(size_t)(r0 + r) * C + c0 + lc];
    }
    __syncthreads();
    #pragma unroll
    for (int i = 0; i < 16; i++) {
        int c = i * 4 + lr;
        dst[(size_t)(c0 + c) * R + r0 + lc] = T[lc][c];
    }
}

// ---------------- kernel 0: slots init -------------------------------------
__global__ __launch_bounds__(256) void k_init_slots(
    const float* __restrict__ slots_init, const float* __restrict__ mu,
    const float* __restrict__ ls, float* __restrict__ slots)
{
    int i = blockIdx.x * 256 + threadIdx.x;
    if (i >= 64 * 7 * 128) return;
    int h = i & 127;
    int bs = i >> 7;
    slots[i] = mu[h] + expf(ls[h]) * slots_init[bs * 132 + h];
}

// ---------------- kernel 1: per-(b,s) slot prep ----------------------------
// sn = LN(slots); q = Wq@sn (via WqT, coalesced); r = scale*Wk^T@q (native Wk);
// rws[b][s][d] = g_in[d]*r[d]; c1 = sum(g_in*r); c2 = sum(b_in*r); zero accums.
__global__ __launch_bounds__(128) void k_slots_prep(
    const float* __restrict__ slots,
    const float* __restrict__ g_s, const float* __restrict__ b_s,
    const float* __restrict__ WqT, const float* __restrict__ Wk,
    const float* __restrict__ g_in, const float* __restrict__ b_in,
    float* __restrict__ rws, float* __restrict__ c1ws, float* __restrict__ c2ws,
    float* __restrict__ yws, float* __restrict__ Zws, float* __restrict__ Aws)
{
    __shared__ float snb[128], qb[128];
    __shared__ float redA[2], redB[2], redC[2], redD[2];
    int bs = blockIdx.x, t = threadIdx.x;
    int b = bs / 7, s = bs - b * 7;
    int lane = t & 63, wvi = t >> 6;
    float sv = slots[bs * 128 + t];
    float sm = sv, sq = sv * sv;
    for (int m = 32; m >= 1; m >>= 1) { sm += __shfl_xor(sm, m); sq += __shfl_xor(sq, m); }
    if (lane == 0) { redA[wvi] = sm; redB[wvi] = sq; }
    __syncthreads();
    sm = redA[0] + redA[1]; sq = redB[0] + redB[1];
    float mean = sm * (1.0f / 128.0f);
    float var  = sq * (1.0f / 128.0f) - mean * mean;
    float rs = rsqrtf(var + LN_EPS_);
    snb[t] = (sv - mean) * rs * g_s[t] + b_s[t];
    __syncthreads();
    float q0 = 0.f, q1 = 0.f;
    for (int d = 0; d < 128; d += 2) {
        q0 += WqT[d * 128 + t] * snb[d];
        q1 += WqT[(d + 1) * 128 + t] * snb[d + 1];
    }
    qb[t] = q0 + q1;
    __syncthreads();
    float r0 = 0.f, r1 = 0.f;
    for (int j = 0; j < 128; j += 2) {
        r0 += Wk[j * 128 + t] * qb[j];
        r1 += Wk[(j + 1) * 128 + t] * qb[j + 1];
    }
    float r = (r0 + r1) * 0.08838834764831845f;   // 128^-0.5
    float rt  = g_in[t] * r;
    float c2v = b_in[t] * r;
    rws[((size_t)b * 8 + s) * 128 + t] = rt;
    float c1p = rt, c2p = c2v;
    for (int m = 32; m >= 1; m >>= 1) { c1p += __shfl_xor(c1p, m); c2p += __shfl_xor(c2p, m); }
    if (lane == 0) { redC[wvi] = c1p; redD[wvi] = c2p; }
    yws[bs * 128 + t] = 0.f;
    __syncthreads();
    if (t == 0) {
        c1ws[b * 8 + s] = redC[0] + redC[1];
        c2ws[b * 8 + s] = redD[0] + redD[1];
        Zws[b * 8 + s] = 0.f;
        Aws[b * 8 + s] = 0.f;
    }
}

// ---------------- kernel 2: streaming attention, all-coalesced -------------
// block=128, tile=128 rows. Cooperative float4 load -> bf16 LDS tile.
// phase1: thread t owns row t (LDS reads, rt bf16 broadcast), softmax, w=p*rs
// phase2: thread (dp=lane, sA=wvi): y[s][d] += sum_n w[n][s]*x[n][d]
__global__ __launch_bounds__(128) void k_attn(
    const float* __restrict__ xin,
    const float* __restrict__ rws, const float* __restrict__ c1ws,
    const float* __restrict__ c2ws,
    float* __restrict__ yws, float* __restrict__ Zws, float* __restrict__ Aws)
{
    __shared__ u32 tile[128 * 66];      // 128 rows x 64 u32 (bf16x2), +2 pad
    __shared__ u32 wlp[128 * 4];        // per-row w, bf16-packed: (s0,s2)(s4,s6)(s1,s3)(s5,0)
    __shared__ u32 rlp[7 * 64];         // rt bf16-packed [s][d/2]
    __shared__ float c1l[8], c2l[8];
    __shared__ float redp[2][8], redw[2][8];
    int t = threadIdx.x;
    int b = blockIdx.y;
    int n0 = blockIdx.x * 128;
    int lane = t & 63, wvi = t >> 6;

    for (int e = t; e < 448; e += 128) {
        int s = e >> 6, j2 = e & 63;
        float ra = rws[b * 1024 + s * 128 + 2 * j2];
        float rb = rws[b * 1024 + s * 128 + 2 * j2 + 1];
        rlp[e] = f2bf(ra) | (f2bf(rb) << 16);
    }
    if (t < 7) { c1l[t] = c1ws[b * 8 + t]; c2l[t] = c2ws[b * 8 + t]; }

    const float4* xg = (const float4*)(xin + ((size_t)b * 4096 + n0) * 128);
    #pragma unroll 8
    for (int j = 0; j < 32; j++) {
        float4 v = xg[j * 128 + t];               // fully coalesced 16B/lane
        int f = j * 128 + t;
        int r = f >> 5, c4 = f & 31;
        u32 lo = f2bf(v.x) | (f2bf(v.y) << 16);
        u32 hi = f2bf(v.z) | (f2bf(v.w) << 16);
        *(uint2*)&tile[r * 66 + 2 * c4] = make_uint2(lo, hi);
    }
    __syncthreads();

    // phase1: per-row dots from LDS
    float a[7];
    #pragma unroll
    for (int s = 0; s < 7; s++) a[s] = 0.f;
    float sm = 0.f, sq = 0.f;
    const uint2* trow = (const uint2*)&tile[t * 66];
    const uint2* rl2 = (const uint2*)rlp;
    #pragma unroll 4
    for (int jj = 0; jj < 32; jj++) {
        uint2 pk = trow[jj];
        float f0 = bflo(pk.x), f1 = bfhi(pk.x), f2v = bflo(pk.y), f3 = bfhi(pk.y);
        sm += (f0 + f1) + (f2v + f3);
        sq += f0 * f0 + f1 * f1 + f2v * f2v + f3 * f3;
        #pragma unroll
        for (int s = 0; s < 7; s++) {
            uint2 rp = rl2[s * 32 + jj];          // wave-uniform broadcast
            a[s] += f0 * bflo(rp.x) + f1 * bfhi(rp.x) + f2v * bflo(rp.y) + f3 * bfhi(rp.y);
        }
    }
    float mean = sm * (1.0f / 128.0f);
    float var  = sq * (1.0f / 128.0f) - mean * mean;
    float rs = rsqrtf(var + LN_EPS_);
    float L[7], mx = -3.4e38f;
    #pragma unroll
    for (int s = 0; s < 7; s++) {
        L[s] = rs * (a[s] - mean * c1l[s]) + c2l[s];
        mx = fmaxf(mx, L[s]);
    }
    float ssum = 0.f;
    #pragma unroll
    for (int s = 0; s < 7; s++) { L[s] = __expf(L[s] - mx); ssum += L[s]; }
    float inv = 1.0f / ssum;
    float p[7], w[7];
    #pragma unroll
    for (int s = 0; s < 7; s++) { p[s] = L[s] * inv + EPS_; w[s] = p[s] * rs; }
    // reductions use the bf16-rounded w actually applied in phase 2
    #pragma unroll
    for (int s = 0; s < 7; s++) {
        float wq = __uint_as_float(f2bf(w[s]) << 16);
        float z = p[s], aa = wq * mean;
        for (int m = 32; m >= 1; m >>= 1) { z += __shfl_xor(z, m); aa += __shfl_xor(aa, m); }
        if (lane == 0) { redp[wvi][s] = z; redw[wvi][s] = aa; }
    }
    wlp[t * 4 + 0] = f2bf(w[0]) | (f2bf(w[2]) << 16);
    wlp[t * 4 + 1] = f2bf(w[4]) | (f2bf(w[6]) << 16);
    wlp[t * 4 + 2] = f2bf(w[1]) | (f2bf(w[3]) << 16);
    wlp[t * 4 + 3] = f2bf(w[5]);
    __syncthreads();
    if (t < 7)                    atomicAdd(&Zws[b * 8 + t], redp[0][t] + redp[1][t]);
    else if (t >= 64 && t < 71) { int s = t - 64; atomicAdd(&Aws[b * 8 + s], redw[0][s] + redw[1][s]); }

    // phase2
    int dp = lane, sA = wvi;
    float accl[4] = {0.f, 0.f, 0.f, 0.f}, acch[4] = {0.f, 0.f, 0.f, 0.f};
    const uint2* wl2 = (const uint2*)wlp;
    #pragma unroll 4
    for (int n = 0; n < 128; n++) {
        u32 xv = tile[n * 66 + dp];               // 2 lanes/bank: free
        float f0 = bflo(xv), f1 = bfhi(xv);
        uint2 wp = wl2[n * 2 + sA];               // wave-uniform broadcast
        float w0 = bflo(wp.x), w1v = bfhi(wp.x), w2v = bflo(wp.y), w3 = bfhi(wp.y);
        accl[0] += f0 * w0;  acch[0] += f1 * w0;
        accl[1] += f0 * w1v; acch[1] += f1 * w1v;
        accl[2] += f0 * w2v; acch[2] += f1 * w2v;
        accl[3] += f0 * w3;  acch[3] += f1 * w3;
    }
    float* yb = yws + (size_t)b * 7 * 128;
    #pragma unroll
    for (int k = 0; k < 4; k++) {
        int s = sA + 2 * k;
        if (s < 7) {
            atomicAdd(&yb[s * 128 + 2 * dp],     accl[k]);
            atomicAdd(&yb[s * 128 + 2 * dp + 1], acch[k]);
        }
    }
}

// ---------------- kernel 3: per-(b,s) slot update (GRU + MLP) --------------
// All weight streams via transposed copies: lane-coalesced L2 reads.
__global__ __launch_bounds__(128) void k_update(
    float* __restrict__ slots, const float* __restrict__ yws,
    const float* __restrict__ Zws, const float* __restrict__ Aws,
    const float* __restrict__ g_in, const float* __restrict__ b_in,
    const float* __restrict__ WvT, const float* __restrict__ WihT,
    const float* __restrict__ WhhT, const float* __restrict__ b_ih,
    const float* __restrict__ b_hh, const float* __restrict__ g_m,
    const float* __restrict__ b_m, const float* __restrict__ w1T,
    const float* __restrict__ bb1, const float* __restrict__ w2T,
    const float* __restrict__ bb2, float* __restrict__ out)
{
    __shared__ float ybuf[128], ub[128], hb[128], lb[128], t1b[256];
    __shared__ float redA[2], redB[2];
    int bs = blockIdx.x, t = threadIdx.x;
    int b = bs / 7, s = bs - b * 7;
    int lane = t & 63, wvi = t >> 6;
    float Z = Zws[b * 8 + s], A = Aws[b * 8 + s];
    float invZ = 1.0f / Z;
    ybuf[t] = g_in[t] * (yws[bs * 128 + t] - A) * invZ + b_in[t];
    hb[t] = slots[bs * 128 + t];
    __syncthreads();
    // u = Wv @ y  via WvT (coalesced), 4 chains
    float a0 = 0.f, a1 = 0.f, a2 = 0.f, a3 = 0.f;
    for (int d = 0; d < 128; d += 4) {
        a0 += WvT[d * 128 + t] * ybuf[d];
        a1 += WvT[(d + 1) * 128 + t] * ybuf[d + 1];
        a2 += WvT[(d + 2) * 128 + t] * ybuf[d + 2];
        a3 += WvT[(d + 3) * 128 + t] * ybuf[d + 3];
    }
    ub[t] = (a0 + a1) + (a2 + a3);
    __syncthreads();
    // GRU gates: 6 independent chains, all coalesced
    float gi0 = b_ih[t], gi1 = b_ih[128 + t], gi2 = b_ih[256 + t];
    float gh0 = b_hh[t], gh1 = b_hh[128 + t], gh2 = b_hh[256 + t];
    for (int d = 0; d < 128; d++) {
        float ud = ub[d], hd = hb[d];
        const float* wi = WihT + (size_t)d * 384 + t;
        const float* wh = WhhT + (size_t)d * 384 + t;
        gi0 += wi[0] * ud; gi1 += wi[128] * ud; gi2 += wi[256] * ud;
        gh0 += wh[0] * hd; gh1 += wh[128] * hd; gh2 += wh[256] * hd;
    }
    float rg = 1.0f / (1.0f + __expf(-(gi0 + gh0)));
    float zg = 1.0f / (1.0f + __expf(-(gi1 + gh1)));
    float ng = tanhf(gi2 + rg * gh2);
    float hv = (1.0f - zg) * ng + zg * hb[t];
    float sm2 = hv, sq2 = hv * hv;
    for (int m = 32; m >= 1; m >>= 1) { sm2 += __shfl_xor(sm2, m); sq2 += __shfl_xor(sq2, m); }
    if (lane == 0) { redA[wvi] = sm2; redB[wvi] = sq2; }
    __syncthreads();
    sm2 = redA[0] + redA[1]; sq2 = redB[0] + redB[1];
    float mean = sm2 * (1.0f / 128.0f);
    float var  = sq2 * (1.0f / 128.0f) - mean * mean;
    float rsq = rsqrtf(var + LN_EPS_);
    lb[t] = (hv - mean) * rsq * g_m[t] + b_m[t];
    __syncthreads();
    // mlp1: 256 outs, 2 chains per thread
    float m0 = bb1[t], m1 = bb1[128 + t];
    for (int d = 0; d < 128; d++) {
        float ld = lb[d];
        const float* wp = w1T + (size_t)d * 256 + t;
        m0 += wp[0] * ld; m1 += wp[128] * ld;
    }
    t1b[t] = fmaxf(m0, 0.0f);
    t1b[128 + t] = fmaxf(m1, 0.0f);
    __syncthreads();
    // mlp2: 128 outs over 256 in, 4 chains
    float o0 = 0.f, o1 = 0.f, o2 = 0.f, o3 = 0.f;
    for (int j = 0; j < 256; j += 4) {
        o0 += w2T[j * 128 + t] * t1b[j];
        o1 += w2T[(j + 1) * 128 + t] * t1b[j + 1];
        o2 += w2T[(j + 2) * 128 + t] * t1b[j + 2];
        o3 += w2T[(j + 3) * 128 + t] * t1b[j + 3];
    }
    float o = hv + bb2[t] + (o0 + o1) + (o2 + o3);
    slots[bs * 128 + t] = o;
    out[bs * 128 + t] = o;
}

extern "C" void kernel_launch(void* const* d_in, const int* in_sizes, int n_in,
                              void* d_out, int out_size, void* d_ws, size_t ws_size,
                              hipStream_t stream) {
    const float* inputs     = (const float*)d_in[0];
    const float* slots_init = (const float*)d_in[1];
    const float* ln_in_g    = (const float*)d_in[2];
    const float* ln_in_b    = (const float*)d_in[3];
    const float* ln_s_g     = (const float*)d_in[4];
    const float* ln_s_b     = (const float*)d_in[5];
    const float* ln_m_g     = (const float*)d_in[6];
    const float* ln_m_b     = (const float*)d_in[7];
    const float* Wq         = (const float*)d_in[8];
    const float* Wk         = (const float*)d_in[9];
    const float* Wv         = (const float*)d_in[10];
    const float* W_ih       = (const float*)d_in[11];
    const float* W_hh       = (const float*)d_in[12];
    const float* b_ih       = (const float*)d_in[13];
    const float* b_hh       = (const float*)d_in[14];
    const float* mlp_w1     = (const float*)d_in[15];
    const float* mlp_b1     = (const float*)d_in[16];
    const float* mlp_w2     = (const float*)d_in[17];
    const float* mlp_b2     = (const float*)d_in[18];
    const float* slots_mu   = (const float*)d_in[19];
    const float* slots_ls   = (const float*)d_in[20];

    char* ws = (char*)d_ws;
    float* slots = (float*)(ws);                  // 229376 B
    float* rws   = (float*)(ws + 229376);         // 262144 B
    float* c1ws  = (float*)(ws + 491520);         // 2048 B
    float* c2ws  = (float*)(ws + 493568);         // 2048 B
    float* yws   = (float*)(ws + 495616);         // 229376 B
    float* Zws   = (float*)(ws + 724992);         // 2048 B
    float* Aws   = (float*)(ws + 727040);         // 2048 B
    float* WqT   = (float*)(ws + 729088);         // 65536 B
    float* WvT   = (float*)(ws + 794624);         // 65536 B
    float* WihT  = (float*)(ws + 860160);         // 196608 B
    float* WhhT  = (float*)(ws + 1056768);        // 196608 B
    float* w1T   = (float*)(ws + 1253376);        // 131072 B
    float* w2T   = (float*)(ws + 1384448);        // 131072 B  -> total 1515520 B

    k_twt<<<48, 256, 0, stream>>>(Wq, Wv, W_ih, W_hh, mlp_w1, mlp_w2,
                                  WqT, WvT, WihT, WhhT, w1T, w2T);
    k_init_slots<<<224, 256, 0, stream>>>(slots_init, slots_mu, slots_ls, slots);
    for (int it = 0; it < 3; it++) {
        k_slots_prep<<<448, 128, 0, stream>>>(slots, ln_s_g, ln_s_b, WqT, Wk,
                                              ln_in_g, ln_in_b,
                                              rws, c1ws, c2ws, yws, Zws, Aws);
        k_attn<<<dim3(32, 64), 128, 0, stream>>>(inputs, rws, c1ws, c2ws, yws, Zws, Aws);
        k_update<<<448, 128, 0, stream>>>(slots, yws, Zws, Aws, ln_in_g, ln_in_b,
                                          WvT, WihT, WhhT, b_ih, b_hh,
                                          ln_m_g, ln_m_b, w1T, mlp_b1, w2T, mlp_b2,
                                          (float*)d_out);
    }
}

// Round 5
// 464.125 us; speedup vs baseline: 1.2573x; 1.0058x over previous
//
#include <hip/hip_runtime.h>
#include <hip/hip_bf16.h>
#include <stdint.h>

typedef unsigned int u32;
typedef unsigned short u16;

#define LN_EPS_ 1e-5f
#define EPS_ 1e-8f

__device__ __forceinline__ float bflo(u32 v){ return __uint_as_float(v << 16); }
__device__ __forceinline__ float bfhi(u32 v){ return __uint_as_float(v & 0xFFFF0000u); }
__device__ __forceinline__ u32 f2bf(float f){
    u32 x = __float_as_uint(f);
    return (x + 0x7FFFu + ((x >> 16) & 1u)) >> 16;
}
__device__ __forceinline__ u32 pack2bf(float a, float b){
    union { __hip_bfloat162 h; u32 u; } cv;
    cv.h = __float22bfloat162_rn(float2{a, b});
    return cv.u;
}

// ---------------- kernel P: one-time weight prep ---------------------------
// bf16 d-pair-packed, output-major (coalesced over lane = output index):
//   Pv [dp<64][o<128]   = pack(Wv[o][2dp], Wv[o][2dp+1])
//   Pih[dp<64][j<384], Phh same
//   Pw1[dp<64][j<256]
//   Pw2[mp<128][o<128]  (K=256)
// plus WqT fp32 (128x128) for slots_prep.
__global__ __launch_bounds__(256) void k_pack(
    const float* __restrict__ Wq, const float* __restrict__ Wv,
    const float* __restrict__ Wih, const float* __restrict__ Whh,
    const float* __restrict__ w1, const float* __restrict__ w2,
    float* __restrict__ WqT, u32* __restrict__ Pv, u32* __restrict__ Pih,
    u32* __restrict__ Phh, u32* __restrict__ Pw1, u32* __restrict__ Pw2)
{
    int i = blockIdx.x * 256 + threadIdx.x;
    if (i < 8192) {                                   // Pv
        int dp = i >> 7, o = i & 127;
        Pv[i] = pack2bf(Wv[o * 128 + 2 * dp], Wv[o * 128 + 2 * dp + 1]);
    } else if (i < 32768) {                           // Pih
        int r = i - 8192; int dp = r / 384, j = r - dp * 384;
        Pih[r] = pack2bf(Wih[j * 128 + 2 * dp], Wih[j * 128 + 2 * dp + 1]);
    } else if (i < 57344) {                           // Phh
        int r = i - 32768; int dp = r / 384, j = r - dp * 384;
        Phh[r] = pack2bf(Whh[j * 128 + 2 * dp], Whh[j * 128 + 2 * dp + 1]);
    } else if (i < 73728) {                           // Pw1
        int r = i - 57344; int dp = r >> 8, j = r & 255;
        Pw1[r] = pack2bf(w1[j * 128 + 2 * dp], w1[j * 128 + 2 * dp + 1]);
    } else if (i < 90112) {                           // Pw2
        int r = i - 73728; int mp = r >> 7, o = r & 127;
        Pw2[r] = pack2bf(w2[o * 256 + 2 * mp], w2[o * 256 + 2 * mp + 1]);
    } else if (i < 106496) {                          // WqT fp32
        int r = i - 90112; int d = r >> 7, o = r & 127;
        WqT[r] = Wq[o * 128 + d];
    }
}

// ---------------- kernel 0: slots init -------------------------------------
__global__ __launch_bounds__(256) void k_init_slots(
    const float* __restrict__ slots_init, const float* __restrict__ mu,
    const float* __restrict__ ls, float* __restrict__ slots)
{
    int i = blockIdx.x * 256 + threadIdx.x;
    if (i >= 64 * 7 * 128) return;
    int h = i & 127;
    int bs = i >> 7;
    slots[i] = mu[h] + expf(ls[h]) * slots_init[bs * 132 + h];
}

// ---------------- kernel 1: per-(b,s) slot prep ----------------------------
__global__ __launch_bounds__(128) void k_slots_prep(
    const float* __restrict__ slots,
    const float* __restrict__ g_s, const float* __restrict__ b_s,
    const float* __restrict__ WqT, const float* __restrict__ Wk,
    const float* __restrict__ g_in, const float* __restrict__ b_in,
    float* __restrict__ rws, float* __restrict__ c1ws, float* __restrict__ c2ws,
    float* __restrict__ yws, float* __restrict__ Zws, float* __restrict__ Aws)
{
    __shared__ float snb[128], qb[128];
    __shared__ float redA[2], redB[2], redC[2], redD[2];
    int bs = blockIdx.x, t = threadIdx.x;
    int b = bs / 7, s = bs - b * 7;
    int lane = t & 63, wvi = t >> 6;
    float sv = slots[bs * 128 + t];
    float sm = sv, sq = sv * sv;
    for (int m = 32; m >= 1; m >>= 1) { sm += __shfl_xor(sm, m); sq += __shfl_xor(sq, m); }
    if (lane == 0) { redA[wvi] = sm; redB[wvi] = sq; }
    __syncthreads();
    sm = redA[0] + redA[1]; sq = redB[0] + redB[1];
    float mean = sm * (1.0f / 128.0f);
    float var  = sq * (1.0f / 128.0f) - mean * mean;
    float rs = rsqrtf(var + LN_EPS_);
    snb[t] = (sv - mean) * rs * g_s[t] + b_s[t];
    __syncthreads();
    float q0 = 0.f, q1 = 0.f;
    #pragma unroll 4
    for (int d = 0; d < 128; d += 2) {
        q0 += WqT[d * 128 + t] * snb[d];
        q1 += WqT[(d + 1) * 128 + t] * snb[d + 1];
    }
    qb[t] = q0 + q1;
    __syncthreads();
    float r0 = 0.f, r1 = 0.f;
    #pragma unroll 4
    for (int j = 0; j < 128; j += 2) {
        r0 += Wk[j * 128 + t] * qb[j];
        r1 += Wk[(j + 1) * 128 + t] * qb[j + 1];
    }
    float r = (r0 + r1) * 0.08838834764831845f;   // 128^-0.5
    float rt  = g_in[t] * r;
    float c2v = b_in[t] * r;
    rws[((size_t)b * 8 + s) * 128 + t] = rt;
    float c1p = rt, c2p = c2v;
    for (int m = 32; m >= 1; m >>= 1) { c1p += __shfl_xor(c1p, m); c2p += __shfl_xor(c2p, m); }
    if (lane == 0) { redC[wvi] = c1p; redD[wvi] = c2p; }
    yws[bs * 128 + t] = 0.f;
    __syncthreads();
    if (t == 0) {
        c1ws[b * 8 + s] = redC[0] + redC[1];
        c2ws[b * 8 + s] = redD[0] + redD[1];
        Zws[b * 8 + s] = 0.f;
        Aws[b * 8 + s] = 0.f;
    }
}

// ---------------- kernel 2: streaming attention, all-coalesced -------------
__global__ __launch_bounds__(128) void k_attn(
    const float* __restrict__ xin,
    const float* __restrict__ rws, const float* __restrict__ c1ws,
    const float* __restrict__ c2ws,
    float* __restrict__ yws, float* __restrict__ Zws, float* __restrict__ Aws)
{
    __shared__ u32 tile[128 * 66];      // 128 rows x 64 u32 (bf16x2), +2 pad
    __shared__ u32 wlp[128 * 4];        // per-row w, bf16-packed: (s0,s2)(s4,s6)(s1,s3)(s5,0)
    __shared__ u32 rlp[7 * 64];         // rt bf16-packed [s][d/2]
    __shared__ float c1l[8], c2l[8];
    __shared__ float redp[2][8], redw[2][8];
    int t = threadIdx.x;
    int b = blockIdx.y;
    int n0 = blockIdx.x * 128;
    int lane = t & 63, wvi = t >> 6;

    for (int e = t; e < 448; e += 128) {
        int s = e >> 6, j2 = e & 63;
        float ra = rws[b * 1024 + s * 128 + 2 * j2];
        float rb = rws[b * 1024 + s * 128 + 2 * j2 + 1];
        rlp[e] = f2bf(ra) | (f2bf(rb) << 16);
    }
    if (t < 7) { c1l[t] = c1ws[b * 8 + t]; c2l[t] = c2ws[b * 8 + t]; }

    const float4* xg = (const float4*)(xin + ((size_t)b * 4096 + n0) * 128);
    #pragma unroll 8
    for (int j = 0; j < 32; j++) {
        float4 v = xg[j * 128 + t];               // fully coalesced 16B/lane
        int f = j * 128 + t;
        int r = f >> 5, c4 = f & 31;
        u32 lo = pack2bf(v.x, v.y);
        u32 hi = pack2bf(v.z, v.w);
        *(uint2*)&tile[r * 66 + 2 * c4] = make_uint2(lo, hi);
    }
    __syncthreads();

    // phase1: per-row dots from LDS
    float a[7];
    #pragma unroll
    for (int s = 0; s < 7; s++) a[s] = 0.f;
    float sm = 0.f, sq = 0.f;
    const uint2* trow = (const uint2*)&tile[t * 66];
    const uint2* rl2 = (const uint2*)rlp;
    #pragma unroll 4
    for (int jj = 0; jj < 32; jj++) {
        uint2 pk = trow[jj];
        float f0 = bflo(pk.x), f1 = bfhi(pk.x), f2v = bflo(pk.y), f3 = bfhi(pk.y);
        sm += (f0 + f1) + (f2v + f3);
        sq += f0 * f0 + f1 * f1 + f2v * f2v + f3 * f3;
        #pragma unroll
        for (int s = 0; s < 7; s++) {
            uint2 rp = rl2[s * 32 + jj];          // wave-uniform broadcast
            a[s] += f0 * bflo(rp.x) + f1 * bfhi(rp.x) + f2v * bflo(rp.y) + f3 * bfhi(rp.y);
        }
    }
    float mean = sm * (1.0f / 128.0f);
    float var  = sq * (1.0f / 128.0f) - mean * mean;
    float rs = rsqrtf(var + LN_EPS_);
    float L[7], mx = -3.4e38f;
    #pragma unroll
    for (int s = 0; s < 7; s++) {
        L[s] = rs * (a[s] - mean * c1l[s]) + c2l[s];
        mx = fmaxf(mx, L[s]);
    }
    float ssum = 0.f;
    #pragma unroll
    for (int s = 0; s < 7; s++) { L[s] = __expf(L[s] - mx); ssum += L[s]; }
    float inv = 1.0f / ssum;
    float p[7], w[7];
    #pragma unroll
    for (int s = 0; s < 7; s++) { p[s] = L[s] * inv + EPS_; w[s] = p[s] * rs; }
    // reductions use the bf16-rounded w actually applied in phase 2
    #pragma unroll
    for (int s = 0; s < 7; s++) {
        float wq = __uint_as_float(f2bf(w[s]) << 16);
        float z = p[s], aa = wq * mean;
        for (int m = 32; m >= 1; m >>= 1) { z += __shfl_xor(z, m); aa += __shfl_xor(aa, m); }
        if (lane == 0) { redp[wvi][s] = z; redw[wvi][s] = aa; }
    }
    wlp[t * 4 + 0] = f2bf(w[0]) | (f2bf(w[2]) << 16);
    wlp[t * 4 + 1] = f2bf(w[4]) | (f2bf(w[6]) << 16);
    wlp[t * 4 + 2] = f2bf(w[1]) | (f2bf(w[3]) << 16);
    wlp[t * 4 + 3] = f2bf(w[5]);
    __syncthreads();
    if (t < 7)                    atomicAdd(&Zws[b * 8 + t], redp[0][t] + redp[1][t]);
    else if (t >= 64 && t < 71) { int s = t - 64; atomicAdd(&Aws[b * 8 + s], redw[0][s] + redw[1][s]); }

    // phase2
    int dp = lane, sA = wvi;
    float accl[4] = {0.f, 0.f, 0.f, 0.f}, acch[4] = {0.f, 0.f, 0.f, 0.f};
    const uint2* wl2 = (const uint2*)wlp;
    #pragma unroll 4
    for (int n = 0; n < 128; n++) {
        u32 xv = tile[n * 66 + dp];               // 2 lanes/bank: free
        float f0 = bflo(xv), f1 = bfhi(xv);
        uint2 wp = wl2[n * 2 + sA];               // wave-uniform broadcast
        float w0 = bflo(wp.x), w1v = bfhi(wp.x), w2v = bflo(wp.y), w3 = bfhi(wp.y);
        accl[0] += f0 * w0;  acch[0] += f1 * w0;
        accl[1] += f0 * w1v; acch[1] += f1 * w1v;
        accl[2] += f0 * w2v; acch[2] += f1 * w2v;
        accl[3] += f0 * w3;  acch[3] += f1 * w3;
    }
    float* yb = yws + (size_t)b * 7 * 128;
    #pragma unroll
    for (int k = 0; k < 4; k++) {
        int s = sA + 2 * k;
        if (s < 7) {
            atomicAdd(&yb[s * 128 + 2 * dp],     accl[k]);
            atomicAdd(&yb[s * 128 + 2 * dp + 1], acch[k]);
        }
    }
}

// ---------------- kernel 3: slot update, 256 threads, bf16 weights ---------
// t<128: "lo" half (h=t). t>=128: "hi" half (h=t-128).
// u: split-K halves; GRU: lo computes gi, hi computes gh (concurrent);
// LN+lb by lo; mlp1: all 256 (one out each); mlp2: split-K halves.
__global__ __launch_bounds__(256) void k_update(
    float* __restrict__ slots, const float* __restrict__ yws,
    const float* __restrict__ Zws, const float* __restrict__ Aws,
    const float* __restrict__ g_in, const float* __restrict__ b_in,
    const u32* __restrict__ Pv, const u32* __restrict__ Pih,
    const u32* __restrict__ Phh, const float* __restrict__ b_ih,
    const float* __restrict__ b_hh, const float* __restrict__ g_m,
    const float* __restrict__ b_m, const u32* __restrict__ Pw1,
    const float* __restrict__ bb1, const u32* __restrict__ Pw2,
    const float* __restrict__ bb2, float* __restrict__ out)
{
    __shared__ float ybuf[128], ub[128], hb[128], lb[128], t1b[256];
    __shared__ float ghx[384];          // gh exchange (hi -> lo)
    __shared__ float up[128], op[128];  // split-K partials
    __shared__ float redA[2], redB[2];
    int bs = blockIdx.x, t = threadIdx.x;
    int b = bs / 7, s = bs - b * 7;
    int h = t & 127, half = t >> 7;
    if (!half) {
        float Z = Zws[b * 8 + s], A = Aws[b * 8 + s];
        ybuf[h] = g_in[h] * (yws[bs * 128 + h] - A) / Z + b_in[h];
        hb[h] = slots[bs * 128 + h];
    }
    __syncthreads();
    // ---- u = Wv @ y : split-K (32 pairs per half) ----
    {
        float a0 = 0.f, a1 = 0.f;
        int dp0 = half * 32;
        #pragma unroll 4
        for (int dp = dp0; dp < dp0 + 32; dp += 2) {
            u32 w0 = Pv[dp * 128 + h];
            u32 w1v = Pv[(dp + 1) * 128 + h];
            a0 += bflo(w0) * ybuf[2 * dp] + bfhi(w0) * ybuf[2 * dp + 1];
            a1 += bflo(w1v) * ybuf[2 * dp + 2] + bfhi(w1v) * ybuf[2 * dp + 3];
        }
        if (half) up[h] = a0 + a1;
        __syncthreads();
        if (!half) ub[h] = (a0 + a1) + up[h];
        __syncthreads();
    }
    // ---- GRU gates: lo -> gi(ub), hi -> gh(hb) ----
    float gv0, gv1, gv2;
    {
        const u32* P = half ? Phh : Pih;
        const float* src = half ? hb : ub;
        gv0 = half ? b_hh[h] : b_ih[h];
        gv1 = half ? b_hh[128 + h] : b_ih[128 + h];
        gv2 = half ? b_hh[256 + h] : b_ih[256 + h];
        #pragma unroll 4
        for (int dp = 0; dp < 64; dp++) {
            float x0 = src[2 * dp], x1 = src[2 * dp + 1];
            u32 w0 = P[dp * 384 + h];
            u32 w1v = P[dp * 384 + 128 + h];
            u32 w2v = P[dp * 384 + 256 + h];
            gv0 += bflo(w0) * x0 + bfhi(w0) * x1;
            gv1 += bflo(w1v) * x0 + bfhi(w1v) * x1;
            gv2 += bflo(w2v) * x0 + bfhi(w2v) * x1;
        }
        if (half) { ghx[h] = gv0; ghx[128 + h] = gv1; ghx[256 + h] = gv2; }
    }
    __syncthreads();
    // ---- combine gates + LN (lo half only) ----
    float hv = 0.f;
    if (!half) {
        float rg = 1.0f / (1.0f + __expf(-(gv0 + ghx[h])));
        float zg = 1.0f / (1.0f + __expf(-(gv1 + ghx[128 + h])));
        float ng = tanhf(gv2 + rg * ghx[256 + h]);
        hv = (1.0f - zg) * ng + zg * hb[h];
        float sm2 = hv, sq2 = hv * hv;
        for (int m = 32; m >= 1; m >>= 1) { sm2 += __shfl_xor(sm2, m); sq2 += __shfl_xor(sq2, m); }
        if ((t & 63) == 0) { redA[t >> 6] = sm2; redB[t >> 6] = sq2; }
    }
    __syncthreads();
    if (!half) {
        float sm2 = redA[0] + redA[1], sq2 = redB[0] + redB[1];
        float mean = sm2 * (1.0f / 128.0f);
        float var  = sq2 * (1.0f / 128.0f) - mean * mean;
        float rsq = rsqrtf(var + LN_EPS_);
        lb[h] = (hv - mean) * rsq * g_m[h] + b_m[h];
    }
    __syncthreads();
    // ---- mlp1: 256 outs, one per thread ----
    {
        float m1 = bb1[t];
        #pragma unroll 4
        for (int dp = 0; dp < 64; dp++) {
            u32 w0 = Pw1[dp * 256 + t];
            m1 += bflo(w0) * lb[2 * dp] + bfhi(w0) * lb[2 * dp + 1];
        }
        t1b[t] = fmaxf(m1, 0.0f);
    }
    __syncthreads();
    // ---- mlp2: 128 outs, split-K (64 pairs per half) ----
    {
        float o0 = 0.f, o1 = 0.f;
        int mp0 = half * 64;
        #pragma unroll 4
        for (int mp = mp0; mp < mp0 + 64; mp += 2) {
            u32 w0 = Pw2[mp * 128 + h];
            u32 w1v = Pw2[(mp + 1) * 128 + h];
            o0 += bflo(w0) * t1b[2 * mp] + bfhi(w0) * t1b[2 * mp + 1];
            o1 += bflo(w1v) * t1b[2 * mp + 2] + bfhi(w1v) * t1b[2 * mp + 3];
        }
        if (half) op[h] = o0 + o1;
        __syncthreads();
        if (!half) {
            float o = hv + bb2[h] + (o0 + o1) + op[h];
            slots[bs * 128 + h] = o;
            out[bs * 128 + h] = o;
        }
    }
}

extern "C" void kernel_launch(void* const* d_in, const int* in_sizes, int n_in,
                              void* d_out, int out_size, void* d_ws, size_t ws_size,
                              hipStream_t stream) {
    const float* inputs     = (const float*)d_in[0];
    const float* slots_init = (const float*)d_in[1];
    const float* ln_in_g    = (const float*)d_in[2];
    const float* ln_in_b    = (const float*)d_in[3];
    const float* ln_s_g     = (const float*)d_in[4];
    const float* ln_s_b     = (const float*)d_in[5];
    const float* ln_m_g     = (const float*)d_in[6];
    const float* ln_m_b     = (const float*)d_in[7];
    const float* Wq         = (const float*)d_in[8];
    const float* Wk         = (const float*)d_in[9];
    const float* Wv         = (const float*)d_in[10];
    const float* W_ih       = (const float*)d_in[11];
    const float* W_hh       = (const float*)d_in[12];
    const float* b_ih       = (const float*)d_in[13];
    const float* b_hh       = (const float*)d_in[14];
    const float* mlp_w1     = (const float*)d_in[15];
    const float* mlp_b1     = (const float*)d_in[16];
    const float* mlp_w2     = (const float*)d_in[17];
    const float* mlp_b2     = (const float*)d_in[18];
    const float* slots_mu   = (const float*)d_in[19];
    const float* slots_ls   = (const float*)d_in[20];

    char* ws = (char*)d_ws;
    float* slots = (float*)(ws);                  // 229376
    float* rws   = (float*)(ws + 229376);         // 262144
    float* c1ws  = (float*)(ws + 491520);         // 2048
    float* c2ws  = (float*)(ws + 493568);         // 2048
    float* yws   = (float*)(ws + 495616);         // 229376
    float* Zws   = (float*)(ws + 724992);         // 2048
    float* Aws   = (float*)(ws + 727040);         // 2048
    float* WqT   = (float*)(ws + 729088);         // 65536
    u32*   Pv    = (u32*)  (ws + 794624);         // 32768
    u32*   Pih   = (u32*)  (ws + 827392);         // 98304
    u32*   Phh   = (u32*)  (ws + 925696);         // 98304
    u32*   Pw1   = (u32*)  (ws + 1024000);        // 65536
    u32*   Pw2   = (u32*)  (ws + 1089536);        // 65536  -> total 1155072 B

    k_pack<<<416, 256, 0, stream>>>(Wq, Wv, W_ih, W_hh, mlp_w1, mlp_w2,
                                    WqT, Pv, Pih, Phh, Pw1, Pw2);
    k_init_slots<<<224, 256, 0, stream>>>(slots_init, slots_mu, slots_ls, slots);
    for (int it = 0; it < 3; it++) {
        k_slots_prep<<<448, 128, 0, stream>>>(slots, ln_s_g, ln_s_b, WqT, Wk,
                                              ln_in_g, ln_in_b,
                                              rws, c1ws, c2ws, yws, Zws, Aws);
        k_attn<<<dim3(32, 64), 128, 0, stream>>>(inputs, rws, c1ws, c2ws, yws, Zws, Aws);
        k_update<<<448, 256, 0, stream>>>(slots, yws, Zws, Aws, ln_in_g, ln_in_b,
                                          Pv, Pih, Phh, b_ih, b_hh,
                                          ln_m_g, ln_m_b, Pw1, mlp_b1, Pw2, mlp_b2,
                                          (float*)d_out);
    }
}

// Round 6
// 426.957 us; speedup vs baseline: 1.3668x; 1.0871x over previous
//
#include <hip/hip_runtime.h>
#include <hip/hip_bf16.h>
#include <stdint.h>

typedef unsigned int u32;
typedef unsigned short u16;

#define LN_EPS_ 1e-5f
#define EPS_ 1e-8f

__device__ __forceinline__ float bflo(u32 v){ return __uint_as_float(v << 16); }
__device__ __forceinline__ float bfhi(u32 v){ return __uint_as_float(v & 0xFFFF0000u); }
__device__ __forceinline__ u32 f2bf(float f){
    u32 x = __float_as_uint(f);
    return (x + 0x7FFFu + ((x >> 16) & 1u)) >> 16;
}
__device__ __forceinline__ u32 pack2bf(float a, float b){
    union { __hip_bfloat162 h; u32 u; } cv;
    cv.h = __float22bfloat162_rn(float2{a, b});
    return cv.u;
}

// ---------------- kernel P: one-time weight prep ---------------------------
__global__ __launch_bounds__(256) void k_pack(
    const float* __restrict__ Wq, const float* __restrict__ Wv,
    const float* __restrict__ Wih, const float* __restrict__ Whh,
    const float* __restrict__ w1, const float* __restrict__ w2,
    float* __restrict__ WqT, u32* __restrict__ Pv, u32* __restrict__ Pih,
    u32* __restrict__ Phh, u32* __restrict__ Pw1, u32* __restrict__ Pw2)
{
    int i = blockIdx.x * 256 + threadIdx.x;
    if (i < 8192) {                                   // Pv
        int dp = i >> 7, o = i & 127;
        Pv[i] = pack2bf(Wv[o * 128 + 2 * dp], Wv[o * 128 + 2 * dp + 1]);
    } else if (i < 32768) {                           // Pih
        int r = i - 8192; int dp = r / 384, j = r - dp * 384;
        Pih[r] = pack2bf(Wih[j * 128 + 2 * dp], Wih[j * 128 + 2 * dp + 1]);
    } else if (i < 57344) {                           // Phh
        int r = i - 32768; int dp = r / 384, j = r - dp * 384;
        Phh[r] = pack2bf(Whh[j * 128 + 2 * dp], Whh[j * 128 + 2 * dp + 1]);
    } else if (i < 73728) {                           // Pw1
        int r = i - 57344; int dp = r >> 8, j = r & 255;
        Pw1[r] = pack2bf(w1[j * 128 + 2 * dp], w1[j * 128 + 2 * dp + 1]);
    } else if (i < 90112) {                           // Pw2
        int r = i - 73728; int mp = r >> 7, o = r & 127;
        Pw2[r] = pack2bf(w2[o * 256 + 2 * mp], w2[o * 256 + 2 * mp + 1]);
    } else if (i < 106496) {                          // WqT fp32
        int r = i - 90112; int d = r >> 7, o = r & 127;
        WqT[r] = Wq[o * 128 + d];
    }
}

// ---------------- prep tail: LN(slot) -> q -> r -> rws/c1/c2, zero accums --
// 256 threads; lo half (t<128) holds nv = new slot value for h = t&127.
__device__ __forceinline__ void prep_tail(
    int b, int s, int h, int half, int t, float nv,
    const float* __restrict__ g_s, const float* __restrict__ b_s,
    const float* __restrict__ WqT, const float* __restrict__ Wk,
    const float* __restrict__ g_in, const float* __restrict__ b_in,
    float* __restrict__ rws, float* __restrict__ c1ws, float* __restrict__ c2ws,
    float* __restrict__ yws, float* __restrict__ Zws, float* __restrict__ Aws,
    float* snb, float* qb, float* xch, float* red4)
{
    if (!half) {
        float smv = nv, sqv = nv * nv;
        for (int m = 32; m >= 1; m >>= 1) { smv += __shfl_xor(smv, m); sqv += __shfl_xor(sqv, m); }
        if ((t & 63) == 0) { red4[(t >> 6) * 2] = smv; red4[(t >> 6) * 2 + 1] = sqv; }
    }
    __syncthreads();
    float mean = (red4[0] + red4[2]) * (1.0f / 128.0f);
    float var  = (red4[1] + red4[3]) * (1.0f / 128.0f) - mean * mean;
    float rsv = rsqrtf(var + LN_EPS_);
    if (!half) snb[h] = (nv - mean) * rsv * g_s[h] + b_s[h];
    __syncthreads();
    // q[h] = sum_d WqT[d][h] * snb[d], split-K over halves
    {
        float q0 = 0.f, q1 = 0.f;
        int d0 = half * 64;
        #pragma unroll 4
        for (int d = d0; d < d0 + 64; d += 2) {
            q0 += WqT[d * 128 + h] * snb[d];
            q1 += WqT[(d + 1) * 128 + h] * snb[d + 1];
        }
        if (half) xch[h] = q0 + q1;
        __syncthreads();
        if (!half) qb[h] = q0 + q1 + xch[h];
        __syncthreads();
    }
    // r[h] = sum_j Wk[j][h] * qb[j], split-K over halves
    float r0 = 0.f, r1 = 0.f;
    int j0 = half * 64;
    #pragma unroll 4
    for (int j = j0; j < j0 + 64; j += 2) {
        r0 += Wk[j * 128 + h] * qb[j];
        r1 += Wk[(j + 1) * 128 + h] * qb[j + 1];
    }
    if (half) xch[h] = r0 + r1;
    __syncthreads();
    if (!half) {
        float r = (r0 + r1 + xch[h]) * 0.08838834764831845f;   // 128^-0.5
        float rt  = g_in[h] * r;
        float c2v = b_in[h] * r;
        rws[((size_t)b * 8 + s) * 128 + h] = rt;
        float c1p = rt, c2p = c2v;
        for (int m = 32; m >= 1; m >>= 1) { c1p += __shfl_xor(c1p, m); c2p += __shfl_xor(c2p, m); }
        if ((t & 63) == 0) { red4[(t >> 6) * 2] = c1p; red4[(t >> 6) * 2 + 1] = c2p; }
        yws[(b * 7 + s) * 128 + h] = 0.f;
    }
    __syncthreads();
    if (t == 0) {
        c1ws[b * 8 + s] = red4[0] + red4[2];
        c2ws[b * 8 + s] = red4[1] + red4[3];
        Zws[b * 8 + s] = 0.f;
        Aws[b * 8 + s] = 0.f;
    }
}

// ---------------- kernel 0: slots init + prep for iter 0 -------------------
__global__ __launch_bounds__(256) void k_init_prep(
    const float* __restrict__ slots_init, const float* __restrict__ mu,
    const float* __restrict__ ls, float* __restrict__ slots,
    const float* __restrict__ g_s, const float* __restrict__ b_s,
    const float* __restrict__ WqT, const float* __restrict__ Wk,
    const float* __restrict__ g_in, const float* __restrict__ b_in,
    float* __restrict__ rws, float* __restrict__ c1ws, float* __restrict__ c2ws,
    float* __restrict__ yws, float* __restrict__ Zws, float* __restrict__ Aws)
{
    __shared__ float snb[128], qb[128], xch[128], red4[4];
    int bs = blockIdx.x, t = threadIdx.x;
    int b = bs / 7, s = bs - b * 7;
    int h = t & 127, half = t >> 7;
    float nv = 0.f;
    if (!half) {
        nv = mu[h] + expf(ls[h]) * slots_init[bs * 132 + h];
        slots[bs * 128 + h] = nv;
    }
    prep_tail(b, s, h, half, t, nv, g_s, b_s, WqT, Wk, g_in, b_in,
              rws, c1ws, c2ws, yws, Zws, Aws, snb, qb, xch, red4);
}

// ---------------- kernel 2: streaming attention, swizzled LDS, 256 thr -----
// tile: 128 rows x 64 u32 bf16-pairs, XOR-swizzled (uint4 col q ^= row&15).
// phase1: thread pair (h=t>>1, dh=t&1) per row, b128 reads, shfl combine.
// phase2: (nh=t>>7, dp=t&63, sA=(t>>6)&1), n-halved, w via b128 n-pairs.
__global__ __launch_bounds__(256) void k_attn(
    const float* __restrict__ xin,
    const float* __restrict__ rws, const float* __restrict__ c1ws,
    const float* __restrict__ c2ws,
    float* __restrict__ yws, float* __restrict__ Zws, float* __restrict__ Aws)
{
    __shared__ u32 tile[8192];          // 32 KB
    __shared__ uint2 wlA[128], wlB[128];
    __shared__ u32 rlp[448];            // bf16-packed r [s][d-pair]
    __shared__ float c1l[8], c2l[8];
    __shared__ float redp[4][8], redw[4][8];
    int t = threadIdx.x;
    int b = blockIdx.y;
    int n0 = blockIdx.x * 128;
    int lane = t & 63, wv = t >> 6;

    for (int e = t; e < 448; e += 256) {
        int s = e >> 6, j2 = e & 63;
        rlp[e] = pack2bf(rws[b * 1024 + s * 128 + 2 * j2],
                         rws[b * 1024 + s * 128 + 2 * j2 + 1]);
    }
    if (t < 7) { c1l[t] = c1ws[b * 8 + t]; c2l[t] = c2ws[b * 8 + t]; }

    const float4* xg = (const float4*)(xin + ((size_t)b * 4096 + n0) * 128);
    #pragma unroll
    for (int j = 0; j < 16; j++) {
        int f = j * 256 + t;
        float4 v = xg[f];
        int r = f >> 5, cp = f & 31;
        int q = cp >> 1, rem = (cp & 1) * 2;
        *(uint2*)&tile[(r * 16 + (q ^ (r & 15))) * 4 + rem] =
            make_uint2(pack2bf(v.x, v.y), pack2bf(v.z, v.w));
    }
    __syncthreads();

    // ---- phase1 ----
    int h = t >> 1, dh = t & 1;
    float a[7] = {0.f,0.f,0.f,0.f,0.f,0.f,0.f};
    float sm = 0.f, sq = 0.f;
    const uint4* rl4 = (const uint4*)rlp;
    #pragma unroll
    for (int jj = 0; jj < 8; jj++) {
        int q = dh * 8 + jj;
        uint4 X = *(const uint4*)&tile[(h * 16 + (q ^ (h & 15))) * 4];
        float xf[8];
        xf[0]=bflo(X.x); xf[1]=bfhi(X.x); xf[2]=bflo(X.y); xf[3]=bfhi(X.y);
        xf[4]=bflo(X.z); xf[5]=bfhi(X.z); xf[6]=bflo(X.w); xf[7]=bfhi(X.w);
        #pragma unroll
        for (int k = 0; k < 8; k++) { sm += xf[k]; sq += xf[k] * xf[k]; }
        #pragma unroll
        for (int s = 0; s < 7; s++) {
            uint4 R = rl4[s * 16 + q];
            a[s] += xf[0]*bflo(R.x) + xf[1]*bfhi(R.x) + xf[2]*bflo(R.y) + xf[3]*bfhi(R.y)
                  + xf[4]*bflo(R.z) + xf[5]*bfhi(R.z) + xf[6]*bflo(R.w) + xf[7]*bfhi(R.w);
        }
    }
    #pragma unroll
    for (int s = 0; s < 7; s++) a[s] += __shfl_xor(a[s], 1);
    sm += __shfl_xor(sm, 1); sq += __shfl_xor(sq, 1);
    float mean = sm * (1.0f / 128.0f);
    float var  = sq * (1.0f / 128.0f) - mean * mean;
    float rs = rsqrtf(var + LN_EPS_);
    float L[7], mx = -3.4e38f;
    #pragma unroll
    for (int s = 0; s < 7; s++) {
        L[s] = rs * (a[s] - mean * c1l[s]) + c2l[s];
        mx = fmaxf(mx, L[s]);
    }
    float ssum = 0.f;
    #pragma unroll
    for (int s = 0; s < 7; s++) { L[s] = __expf(L[s] - mx); ssum += L[s]; }
    float inv = 1.0f / ssum;
    float p[7], w[7];
    #pragma unroll
    for (int s = 0; s < 7; s++) { p[s] = L[s] * inv + EPS_; w[s] = p[s] * rs; }
    if (!dh) {
        wlA[h] = make_uint2(f2bf(w[0]) | (f2bf(w[2]) << 16),
                            f2bf(w[4]) | (f2bf(w[6]) << 16));
        wlB[h] = make_uint2(f2bf(w[1]) | (f2bf(w[3]) << 16),
                            f2bf(w[5]));
    }
    #pragma unroll
    for (int s = 0; s < 7; s++) {
        float wq = __uint_as_float(f2bf(w[s]) << 16);
        float z = p[s], aa = wq * mean;
        for (int m = 32; m >= 1; m >>= 1) { z += __shfl_xor(z, m); aa += __shfl_xor(aa, m); }
        if (lane == 0) { redp[wv][s] = z; redw[wv][s] = aa; }
    }
    __syncthreads();
    // rows duplicated x2 in the wave reduction -> 0.5 factor
    if (t < 7)
        atomicAdd(&Zws[b * 8 + t],
                  0.5f * (redp[0][t] + redp[1][t] + redp[2][t] + redp[3][t]));
    else if (t >= 64 && t < 71) {
        int s = t - 64;
        atomicAdd(&Aws[b * 8 + s],
                  0.5f * (redw[0][s] + redw[1][s] + redw[2][s] + redw[3][s]));
    }

    // ---- phase2 ----
    int nh = t >> 7, dp = t & 63, sA = (t >> 6) & 1;
    const uint2* wsrc = sA ? wlB : wlA;
    float accl[4] = {0.f,0.f,0.f,0.f}, acch[4] = {0.f,0.f,0.f,0.f};
    int nbeg = nh * 64;
    #pragma unroll 4
    for (int n = nbeg; n < nbeg + 64; n += 2) {
        uint4 Wp = *(const uint4*)&wsrc[n];
        u32 x0 = tile[(n * 16 + ((dp >> 2) ^ (n & 15))) * 4 + (dp & 3)];
        u32 x1 = tile[((n + 1) * 16 + ((dp >> 2) ^ ((n + 1) & 15))) * 4 + (dp & 3)];
        float f0 = bflo(x0), f1 = bfhi(x0);
        accl[0] += f0 * bflo(Wp.x); acch[0] += f1 * bflo(Wp.x);
        accl[1] += f0 * bfhi(Wp.x); acch[1] += f1 * bfhi(Wp.x);
        accl[2] += f0 * bflo(Wp.y); acch[2] += f1 * bflo(Wp.y);
        accl[3] += f0 * bfhi(Wp.y); acch[3] += f1 * bfhi(Wp.y);
        f0 = bflo(x1); f1 = bfhi(x1);
        accl[0] += f0 * bflo(Wp.z); acch[0] += f1 * bflo(Wp.z);
        accl[1] += f0 * bfhi(Wp.z); acch[1] += f1 * bfhi(Wp.z);
        accl[2] += f0 * bflo(Wp.w); acch[2] += f1 * bflo(Wp.w);
        accl[3] += f0 * bfhi(Wp.w); acch[3] += f1 * bfhi(Wp.w);
    }
    float* yb = yws + (size_t)b * 7 * 128;
    #pragma unroll
    for (int k = 0; k < 4; k++) {
        int s = sA + 2 * k;
        if (s < 7) {
            atomicAdd(&yb[s * 128 + 2 * dp],     accl[k]);
            atomicAdd(&yb[s * 128 + 2 * dp + 1], acch[k]);
        }
    }
}

// ---------------- kernel 3: slot update (GRU + MLP) + fused next-prep ------
__global__ __launch_bounds__(256) void k_update(
    float* __restrict__ slots, const float* __restrict__ yws,
    float* __restrict__ Zws, float* __restrict__ Aws,
    const float* __restrict__ g_in, const float* __restrict__ b_in,
    const u32* __restrict__ Pv, const u32* __restrict__ Pih,
    const u32* __restrict__ Phh, const float* __restrict__ b_ih,
    const float* __restrict__ b_hh, const float* __restrict__ g_m,
    const float* __restrict__ b_m, const u32* __restrict__ Pw1,
    const float* __restrict__ bb1, const u32* __restrict__ Pw2,
    const float* __restrict__ bb2, float* __restrict__ out,
    const float* __restrict__ g_s, const float* __restrict__ b_s,
    const float* __restrict__ WqT, const float* __restrict__ Wk,
    float* __restrict__ rws, float* __restrict__ c1ws, float* __restrict__ c2ws,
    float* __restrict__ ywz, int do_prep)
{
    __shared__ float ybuf[128], ub[128], hb[128], lb[128], t1b[256];
    __shared__ float ghx[384];
    __shared__ float up[128], op[128];
    __shared__ float redA[2], redB[2];
    __shared__ float snb[128], qb[128], xch[128], red4[4];
    int bs = blockIdx.x, t = threadIdx.x;
    int b = bs / 7, s = bs - b * 7;
    int h = t & 127, half = t >> 7;
    if (!half) {
        float Z = Zws[b * 8 + s], A = Aws[b * 8 + s];
        ybuf[h] = g_in[h] * (yws[bs * 128 + h] - A) / Z + b_in[h];
        hb[h] = slots[bs * 128 + h];
    }
    __syncthreads();
    // ---- u = Wv @ y : split-K ----
    {
        float a0 = 0.f, a1 = 0.f;
        int dp0 = half * 32;
        #pragma unroll 4
        for (int dp = dp0; dp < dp0 + 32; dp += 2) {
            u32 w0 = Pv[dp * 128 + h];
            u32 w1v = Pv[(dp + 1) * 128 + h];
            a0 += bflo(w0) * ybuf[2 * dp] + bfhi(w0) * ybuf[2 * dp + 1];
            a1 += bflo(w1v) * ybuf[2 * dp + 2] + bfhi(w1v) * ybuf[2 * dp + 3];
        }
        if (half) up[h] = a0 + a1;
        __syncthreads();
        if (!half) ub[h] = (a0 + a1) + up[h];
        __syncthreads();
    }
    // ---- GRU gates: lo -> gi(ub), hi -> gh(hb) ----
    float gv0, gv1, gv2;
    {
        const u32* P = half ? Phh : Pih;
        const float* src = half ? hb : ub;
        gv0 = half ? b_hh[h] : b_ih[h];
        gv1 = half ? b_hh[128 + h] : b_ih[128 + h];
        gv2 = half ? b_hh[256 + h] : b_ih[256 + h];
        #pragma unroll 4
        for (int dp = 0; dp < 64; dp++) {
            float x0 = src[2 * dp], x1 = src[2 * dp + 1];
            u32 w0 = P[dp * 384 + h];
            u32 w1v = P[dp * 384 + 128 + h];
            u32 w2v = P[dp * 384 + 256 + h];
            gv0 += bflo(w0) * x0 + bfhi(w0) * x1;
            gv1 += bflo(w1v) * x0 + bfhi(w1v) * x1;
            gv2 += bflo(w2v) * x0 + bfhi(w2v) * x1;
        }
        if (half) { ghx[h] = gv0; ghx[128 + h] = gv1; ghx[256 + h] = gv2; }
    }
    __syncthreads();
    float hv = 0.f;
    if (!half) {
        float rg = 1.0f / (1.0f + __expf(-(gv0 + ghx[h])));
        float zg = 1.0f / (1.0f + __expf(-(gv1 + ghx[128 + h])));
        float ng = tanhf(gv2 + rg * ghx[256 + h]);
        hv = (1.0f - zg) * ng + zg * hb[h];
        float sm2 = hv, sq2 = hv * hv;
        for (int m = 32; m >= 1; m >>= 1) { sm2 += __shfl_xor(sm2, m); sq2 += __shfl_xor(sq2, m); }
        if ((t & 63) == 0) { redA[t >> 6] = sm2; redB[t >> 6] = sq2; }
    }
    __syncthreads();
    if (!half) {
        float sm2 = redA[0] + redA[1], sq2 = redB[0] + redB[1];
        float mean = sm2 * (1.0f / 128.0f);
        float var  = sq2 * (1.0f / 128.0f) - mean * mean;
        float rsq = rsqrtf(var + LN_EPS_);
        lb[h] = (hv - mean) * rsq * g_m[h] + b_m[h];
    }
    __syncthreads();
    // ---- mlp1: 256 outs, one per thread ----
    {
        float m1 = bb1[t];
        #pragma unroll 4
        for (int dp = 0; dp < 64; dp++) {
            u32 w0 = Pw1[dp * 256 + t];
            m1 += bflo(w0) * lb[2 * dp] + bfhi(w0) * lb[2 * dp + 1];
        }
        t1b[t] = fmaxf(m1, 0.0f);
    }
    __syncthreads();
    // ---- mlp2: 128 outs, split-K ----
    float nv = 0.f;
    {
        float o0 = 0.f, o1 = 0.f;
        int mp0 = half * 64;
        #pragma unroll 4
        for (int mp = mp0; mp < mp0 + 64; mp += 2) {
            u32 w0 = Pw2[mp * 128 + h];
            u32 w1v = Pw2[(mp + 1) * 128 + h];
            o0 += bflo(w0) * t1b[2 * mp] + bfhi(w0) * t1b[2 * mp + 1];
            o1 += bflo(w1v) * t1b[2 * mp + 2] + bfhi(w1v) * t1b[2 * mp + 3];
        }
        if (half) op[h] = o0 + o1;
        __syncthreads();
        if (!half) {
            nv = hv + bb2[h] + (o0 + o1) + op[h];
            slots[bs * 128 + h] = nv;
            out[bs * 128 + h] = nv;
        }
    }
    if (do_prep) {
        __syncthreads();
        prep_tail(b, s, h, half, t, nv, g_s, b_s, WqT, Wk, g_in, b_in,
                  rws, c1ws, c2ws, ywz, Zws, Aws, snb, qb, xch, red4);
    }
}

extern "C" void kernel_launch(void* const* d_in, const int* in_sizes, int n_in,
                              void* d_out, int out_size, void* d_ws, size_t ws_size,
                              hipStream_t stream) {
    const float* inputs     = (const float*)d_in[0];
    const float* slots_init = (const float*)d_in[1];
    const float* ln_in_g    = (const float*)d_in[2];
    const float* ln_in_b    = (const float*)d_in[3];
    const float* ln_s_g     = (const float*)d_in[4];
    const float* ln_s_b     = (const float*)d_in[5];
    const float* ln_m_g     = (const float*)d_in[6];
    const float* ln_m_b     = (const float*)d_in[7];
    const float* Wq         = (const float*)d_in[8];
    const float* Wk         = (const float*)d_in[9];
    const float* Wv         = (const float*)d_in[10];
    const float* W_ih       = (const float*)d_in[11];
    const float* W_hh       = (const float*)d_in[12];
    const float* b_ih       = (const float*)d_in[13];
    const float* b_hh       = (const float*)d_in[14];
    const float* mlp_w1     = (const float*)d_in[15];
    const float* mlp_b1     = (const float*)d_in[16];
    const float* mlp_w2     = (const float*)d_in[17];
    const float* mlp_b2     = (const float*)d_in[18];
    const float* slots_mu   = (const float*)d_in[19];
    const float* slots_ls   = (const float*)d_in[20];

    char* ws = (char*)d_ws;
    float* slots = (float*)(ws);                  // 229376
    float* rws   = (float*)(ws + 229376);         // 262144
    float* c1ws  = (float*)(ws + 491520);         // 2048
    float* c2ws  = (float*)(ws + 493568);         // 2048
    float* yws   = (float*)(ws + 495616);         // 229376
    float* Zws   = (float*)(ws + 724992);         // 2048
    float* Aws   = (float*)(ws + 727040);         // 2048
    float* WqT   = (float*)(ws + 729088);         // 65536
    u32*   Pv    = (u32*)  (ws + 794624);         // 32768
    u32*   Pih   = (u32*)  (ws + 827392);         // 98304
    u32*   Phh   = (u32*)  (ws + 925696);         // 98304
    u32*   Pw1   = (u32*)  (ws + 1024000);        // 65536
    u32*   Pw2   = (u32*)  (ws + 1089536);        // 65536  -> total 1155072 B

    k_pack<<<416, 256, 0, stream>>>(Wq, Wv, W_ih, W_hh, mlp_w1, mlp_w2,
                                    WqT, Pv, Pih, Phh, Pw1, Pw2);
    k_init_prep<<<448, 256, 0, stream>>>(slots_init, slots_mu, slots_ls, slots,
                                         ln_s_g, ln_s_b, WqT, Wk, ln_in_g, ln_in_b,
                                         rws, c1ws, c2ws, yws, Zws, Aws);
    for (int it = 0; it < 3; it++) {
        k_attn<<<dim3(32, 64), 256, 0, stream>>>(inputs, rws, c1ws, c2ws, yws, Zws, Aws);
        k_update<<<448, 256, 0, stream>>>(slots, yws, Zws, Aws, ln_in_g, ln_in_b,
                                          Pv, Pih, Phh, b_ih, b_hh,
                                          ln_m_g, ln_m_b, Pw1, mlp_b1, Pw2, mlp_b2,
                                          (float*)d_out,
                                          ln_s_g, ln_s_b, WqT, Wk,
                                          rws, c1ws, c2ws, yws, (it < 2) ? 1 : 0);
    }
}